// Round 3
// baseline (591.431 us; speedup 1.0000x reference)
//
#include <hip/hip_runtime.h>

constexpr int NN  = 100000;
constexpr int NE  = 1600000;
constexpr int TOT = NE + NN;

// ---------- bf16 helpers (bit-level, zero-cost) ----------
__device__ inline float bflo(unsigned int w) { unsigned int x = w << 16; return __builtin_bit_cast(float, x); }
__device__ inline float bfhi(unsigned int w) { unsigned int x = w & 0xffff0000u; return __builtin_bit_cast(float, x); }
__device__ inline unsigned int f2bf(float f) {  // round-to-nearest-even, bits in low 16
  unsigned int x = __builtin_bit_cast(unsigned int, f);
  return (x + 0x7fffu + ((x >> 16) & 1u)) >> 16;
}

// ---------- edge_index dtype probe ----------
// int64 with values < 2^17 -> all odd 32-bit words are 0. int32 random ids -> virtually never.
__global__ __launch_bounds__(256) void k_detect(const unsigned int* __restrict__ ei, int* __restrict__ flag) {
  __shared__ int nz;
  if (threadIdx.x == 0) nz = 0;
  __syncthreads();
  if (ei[threadIdx.x * 2 + 1] != 0u) atomicAdd(&nz, 1);
  __syncthreads();
  if (threadIdx.x == 0) flag[0] = (nz == 0) ? 1 : 0;
}

__device__ inline int load_idx(const void* ei, long long i, int is64) {
  return is64 ? (int)((const long long*)ei)[i] : ((const int*)ei)[i];
}

// ---------- CSR build ----------
__global__ __launch_bounds__(256) void k_init_counts(int* __restrict__ counts) {
  int i = blockIdx.x * 256 + threadIdx.x;
  if (i < NN) counts[i] = 1;  // self-loop
}

__global__ __launch_bounds__(256) void k_count(const void* __restrict__ ei, const int* __restrict__ flag,
                                               int* __restrict__ counts) {
  int is64 = flag[0];
  int e = blockIdx.x * 256 + threadIdx.x;
  if (e < NE) atomicAdd(&counts[load_idx(ei, (long long)NE + e, is64)], 1);
}

__global__ __launch_bounds__(256) void k_block_reduce(const int* __restrict__ counts, int* __restrict__ blockSums) {
  __shared__ int s[256];
  int i = blockIdx.x * 256 + threadIdx.x;
  s[threadIdx.x] = (i < NN) ? counts[i] : 0;
  __syncthreads();
  for (int off = 128; off > 0; off >>= 1) {
    if (threadIdx.x < off) s[threadIdx.x] += s[threadIdx.x + off];
    __syncthreads();
  }
  if (threadIdx.x == 0) blockSums[blockIdx.x] = s[0];
}

__global__ __launch_bounds__(512) void k_scan_top(int* __restrict__ blockSums, int* __restrict__ row_start, int nblk) {
  __shared__ int s[512];
  int t = threadIdx.x;
  int v = (t < nblk) ? blockSums[t] : 0;
  s[t] = v;
  __syncthreads();
  for (int off = 1; off < 512; off <<= 1) {
    int u = (t >= off) ? s[t - off] : 0;
    __syncthreads();
    s[t] += u;
    __syncthreads();
  }
  if (t < nblk) blockSums[t] = s[t] - v;  // exclusive block offsets, in place
  if (t == 0) row_start[NN] = TOT;
}

// counts and cursor share one buffer: read count, then overwrite with fill cursor.
__global__ __launch_bounds__(256) void k_scan_fill(const int* __restrict__ blockOff,
                                                   int* __restrict__ cnt_cur,
                                                   int* __restrict__ row_start,
                                                   float* __restrict__ dinv, int* __restrict__ csr_src) {
  __shared__ int s[256];
  int i = blockIdx.x * 256 + threadIdx.x;
  int c = (i < NN) ? cnt_cur[i] : 0;
  s[threadIdx.x] = c;
  __syncthreads();
  for (int off = 1; off < 256; off <<= 1) {
    int u = (threadIdx.x >= off) ? s[threadIdx.x - off] : 0;
    __syncthreads();
    s[threadIdx.x] += u;
    __syncthreads();
  }
  if (i < NN) {
    int start = blockOff[blockIdx.x] + s[threadIdx.x] - c;  // exclusive scan
    row_start[i]  = start;
    cnt_cur[i]    = start + 1;       // cursor; slot 0 holds the self-loop
    csr_src[start] = i;
    dinv[i] = rsqrtf((float)c);      // deg includes self-loop, >= 1
  }
}

__global__ __launch_bounds__(256) void k_fill(const void* __restrict__ ei, const int* __restrict__ flag,
                                              int* __restrict__ cursor, int* __restrict__ csr_src) {
  int is64 = flag[0];
  int e = blockIdx.x * 256 + threadIdx.x;
  if (e < NE) {
    int sidx = load_idx(ei, e, is64);
    int d    = load_idx(ei, (long long)NE + e, is64);
    int p = atomicAdd(&cursor[d], 1);
    csr_src[p] = sidx;
  }
}

// ---------- fp32-accum GEMM: Y[N,OUTC] = X[N,128] @ W[128,OUTC]; X/Y fp32 or bf16 ----------
template<int OUTC, bool IN_BF, bool OUT_BF>
__global__ __launch_bounds__(256) void k_gemm(const void* __restrict__ Xv,
                                              const float* __restrict__ W,
                                              void* __restrict__ Yv, int nrows) {
  constexpr int CG   = OUTC / 8;   // col groups of 8
  constexpr int RG   = 256 / CG;   // row groups of 4
  constexpr int ROWS = RG * 4;     // rows per block
  constexpr int KB   = 64;         // k-chunk
  constexpr int XS   = 65;         // padded LDS stride
  __shared__ float sW[KB * OUTC];
  __shared__ float sX[ROWS * XS];
  const int tid  = threadIdx.x;
  const int row0 = blockIdx.x * ROWS;
  const int cg = tid % CG, rg = tid / CG;
  float acc[4][8] = {};

  for (int kc = 0; kc < 128; kc += KB) {
    __syncthreads();
    for (int i = tid * 4; i < KB * OUTC; i += 1024)
      *(float4*)&sW[i] = *(const float4*)&W[kc * OUTC + i];
    if constexpr (!IN_BF) {
      const float* X = (const float*)Xv;
      for (int idx = tid; idx < ROWS * (KB / 4); idx += 256) {
        int r = idx / (KB / 4), k4 = idx % (KB / 4);
        int gr = row0 + r;
        float4 v = make_float4(0.f, 0.f, 0.f, 0.f);
        if (gr < nrows) v = *(const float4*)&X[(size_t)gr * 128 + kc + k4 * 4];
        float* p = &sX[r * XS + k4 * 4];
        p[0] = v.x; p[1] = v.y; p[2] = v.z; p[3] = v.w;
      }
    } else {
      const unsigned short* X = (const unsigned short*)Xv;
      for (int idx = tid; idx < ROWS * (KB / 8); idx += 256) {
        int r = idx / (KB / 8), g = idx % (KB / 8);
        int gr = row0 + r;
        uint4 v = make_uint4(0u, 0u, 0u, 0u);
        if (gr < nrows) v = *(const uint4*)&X[(size_t)gr * 128 + kc + g * 8];
        float* p = &sX[r * XS + g * 8];
        p[0] = bflo(v.x); p[1] = bfhi(v.x); p[2] = bflo(v.y); p[3] = bfhi(v.y);
        p[4] = bflo(v.z); p[5] = bfhi(v.z); p[6] = bflo(v.w); p[7] = bfhi(v.w);
      }
    }
    __syncthreads();
    #pragma unroll 8
    for (int k = 0; k < KB; k++) {
      float aa[4];
      aa[0] = sX[(rg * 4 + 0) * XS + k];
      aa[1] = sX[(rg * 4 + 1) * XS + k];
      aa[2] = sX[(rg * 4 + 2) * XS + k];
      aa[3] = sX[(rg * 4 + 3) * XS + k];
      float4 b0 = *(const float4*)&sW[k * OUTC + cg * 8];
      float4 b1 = *(const float4*)&sW[k * OUTC + cg * 8 + 4];
      float bb[8] = {b0.x, b0.y, b0.z, b0.w, b1.x, b1.y, b1.z, b1.w};
      #pragma unroll
      for (int i2 = 0; i2 < 4; i2++)
        #pragma unroll
        for (int j2 = 0; j2 < 8; j2++)
          acc[i2][j2] = fmaf(aa[i2], bb[j2], acc[i2][j2]);
    }
  }
  #pragma unroll
  for (int i2 = 0; i2 < 4; i2++) {
    int gr = row0 + rg * 4 + i2;
    if (gr < nrows) {
      if constexpr (OUT_BF) {
        unsigned short* Y = (unsigned short*)Yv;
        uint4 o;
        o.x = f2bf(acc[i2][0]) | (f2bf(acc[i2][1]) << 16);
        o.y = f2bf(acc[i2][2]) | (f2bf(acc[i2][3]) << 16);
        o.z = f2bf(acc[i2][4]) | (f2bf(acc[i2][5]) << 16);
        o.w = f2bf(acc[i2][6]) | (f2bf(acc[i2][7]) << 16);
        *(uint4*)&Y[(size_t)gr * OUTC + cg * 8] = o;
      } else {
        float* Y = (float*)Yv;
        *(float4*)&Y[(size_t)gr * OUTC + cg * 8]     = make_float4(acc[i2][0], acc[i2][1], acc[i2][2], acc[i2][3]);
        *(float4*)&Y[(size_t)gr * OUTC + cg * 8 + 4] = make_float4(acc[i2][4], acc[i2][5], acc[i2][6], acc[i2][7]);
      }
    }
  }
}

// ---------- aggregation: out[n] = dinv[n] * sum_{s in CSR(n)} dinv[s]*h[s] + b ----------
template<int F, bool BF, bool RELU>
__global__ __launch_bounds__(256) void k_agg(const void* __restrict__ hv, const float* __restrict__ dinv,
                                             const int* __restrict__ row_start, const int* __restrict__ csr_src,
                                             const float* __restrict__ bias, void* __restrict__ outv) {
  constexpr int EPL = BF ? 8 : 4;   // elements per lane (16B each)
  constexpr int LPN = F / EPL;      // lanes per node
  constexpr int NPB = 256 / LPN;    // nodes per block
  int node = blockIdx.x * NPB + threadIdx.x / LPN;
  int lane = threadIdx.x % LPN;
  if (node >= NN) return;
  int j0 = row_start[node], j1 = row_start[node + 1];
  float acc[EPL] = {};
  if constexpr (BF) {
    const unsigned short* h = (const unsigned short*)hv;
    for (int j = j0; j < j1; j++) {
      int s = csr_src[j];
      float w = dinv[s];
      uint4 v = *(const uint4*)&h[(size_t)s * F + lane * 8];
      acc[0] = fmaf(w, bflo(v.x), acc[0]);
      acc[1] = fmaf(w, bfhi(v.x), acc[1]);
      acc[2] = fmaf(w, bflo(v.y), acc[2]);
      acc[3] = fmaf(w, bfhi(v.y), acc[3]);
      acc[4] = fmaf(w, bflo(v.z), acc[4]);
      acc[5] = fmaf(w, bfhi(v.z), acc[5]);
      acc[6] = fmaf(w, bflo(v.w), acc[6]);
      acc[7] = fmaf(w, bfhi(v.w), acc[7]);
    }
  } else {
    const float* h = (const float*)hv;
    for (int j = j0; j < j1; j++) {
      int s = csr_src[j];
      float w = dinv[s];
      float4 v = *(const float4*)&h[(size_t)s * F + lane * 4];
      acc[0] = fmaf(w, v.x, acc[0]);
      acc[1] = fmaf(w, v.y, acc[1]);
      acc[2] = fmaf(w, v.z, acc[2]);
      acc[3] = fmaf(w, v.w, acc[3]);
    }
  }
  float dn = dinv[node];
  float o[EPL];
  #pragma unroll
  for (int t = 0; t < EPL; t++) {
    o[t] = fmaf(dn, acc[t], bias[lane * EPL + t]);
    if (RELU) o[t] = fmaxf(o[t], 0.f);
  }
  if constexpr (BF) {
    unsigned short* out = (unsigned short*)outv;
    uint4 w;
    w.x = f2bf(o[0]) | (f2bf(o[1]) << 16);
    w.y = f2bf(o[2]) | (f2bf(o[3]) << 16);
    w.z = f2bf(o[4]) | (f2bf(o[5]) << 16);
    w.w = f2bf(o[6]) | (f2bf(o[7]) << 16);
    *(uint4*)&out[(size_t)node * F + lane * 8] = w;
  } else {
    float* out = (float*)outv;
    *(float4*)&out[(size_t)node * F + lane * 4] = make_float4(o[0], o[1], o[2], o[3]);
  }
}

// ---------- launch ----------
extern "C" void kernel_launch(void* const* d_in, const int* in_sizes, int n_in,
                              void* d_out, int out_size, void* d_ws, size_t ws_size,
                              hipStream_t stream) {
  const float* x  = (const float*)d_in[0];
  const void*  ei = d_in[1];
  const float* W1 = (const float*)d_in[2];
  const float* b1 = (const float*)d_in[3];
  const float* W2 = (const float*)d_in[4];
  const float* b2 = (const float*)d_in[5];
  float* out = (float*)d_out;

  char* ws = (char*)d_ws;
  size_t off = 0;
  auto wsalloc = [&](size_t bytes) -> void* {
    void* p = ws + off;
    off += (bytes + 255) & ~(size_t)255;
    return p;
  };
  int*   row_start = (int*)   wsalloc((NN + 1) * sizeof(int));
  int*   cnt_cur   = (int*)   wsalloc(NN * sizeof(int));
  int*   blockSums = (int*)   wsalloc(512 * sizeof(int));
  float* dinv      = (float*) wsalloc(NN * sizeof(float));
  int*   flag      = (int*)   wsalloc(64);
  int*   csr_src   = (int*)   wsalloc((size_t)TOT * sizeof(int));
  size_t fixed_end = off;

  // fp32 intermediates need 2 * N*128*4 = 102.4 MB beyond fixed_end; bf16 needs half.
  bool f32path = ws_size >= fixed_end + 2 * (size_t)NN * 128 * sizeof(float) + 1024;

  constexpr int NBLK = (NN + 255) / 256;  // 391
  constexpr int EBLK = (NE + 255) / 256;  // 6250

  k_detect<<<1, 256, 0, stream>>>((const unsigned int*)ei, flag);
  k_init_counts<<<NBLK, 256, 0, stream>>>(cnt_cur);
  k_count<<<EBLK, 256, 0, stream>>>(ei, flag, cnt_cur);
  k_block_reduce<<<NBLK, 256, 0, stream>>>(cnt_cur, blockSums);
  k_scan_top<<<1, 512, 0, stream>>>(blockSums, row_start, NBLK);
  k_scan_fill<<<NBLK, 256, 0, stream>>>(blockSums, cnt_cur, row_start, dinv, csr_src);
  k_fill<<<EBLK, 256, 0, stream>>>(ei, flag, cnt_cur, csr_src);

  if (f32path) {
    float* h1   = (float*)wsalloc((size_t)NN * 128 * sizeof(float));
    float* hmid = (float*)wsalloc((size_t)NN * 128 * sizeof(float));
    float* hL2  = h1;  // [N,64] fp32 reuses h1 (dead by then)
    k_gemm<128, false, false><<<(NN + 63) / 64, 256, 0, stream>>>(x, W1, h1, NN);
    k_agg<128, false, true><<<(NN + 7) / 8, 256, 0, stream>>>(h1, dinv, row_start, csr_src, b1, hmid);
    k_gemm<64, false, false><<<(NN + 127) / 128, 256, 0, stream>>>(hmid, W2, hL2, NN);
    k_agg<64, false, false><<<(NN + 15) / 16, 256, 0, stream>>>(hL2, dinv, row_start, csr_src, b2, out);
  } else {
    unsigned short* h1   = (unsigned short*)wsalloc((size_t)NN * 128 * sizeof(unsigned short));
    unsigned short* hmid = (unsigned short*)wsalloc((size_t)NN * 128 * sizeof(unsigned short));
    float*          hL2  = (float*)h1;  // [N,64] fp32 = same bytes as h1; h1 dead by then
    k_gemm<128, false, true><<<(NN + 63) / 64, 256, 0, stream>>>(x, W1, h1, NN);
    k_agg<128, true, true><<<(NN + 15) / 16, 256, 0, stream>>>(h1, dinv, row_start, csr_src, b1, hmid);
    k_gemm<64, true, false><<<(NN + 127) / 128, 256, 0, stream>>>(hmid, W2, hL2, NN);
    k_agg<64, false, false><<<(NN + 15) / 16, 256, 0, stream>>>(hL2, dinv, row_start, csr_src, b2, out);
  }
}

// Round 4
// 487.921 us; speedup vs baseline: 1.2121x; 1.2121x over previous
//
#include <hip/hip_runtime.h>
#include <hip/hip_fp16.h>

constexpr int NN  = 100000;
constexpr int NE  = 1600000;
constexpr int TOT = NE + NN;
constexpr int PAD = 16;          // counters padded to 64B to kill same-line atomic contention
constexpr int EPT = 4;           // edges per thread in count/fill

// ---------- fp16 helpers ----------
__device__ inline float2 h2f2(unsigned int u) {
  __half2 h = __builtin_bit_cast(__half2, u);
  return __half22float2(h);
}
__device__ inline unsigned int f2h2(float a, float b) {
  __half2 h = __floats2half2_rn(a, b);
  return __builtin_bit_cast(unsigned int, h);
}

// ---------- edge_index dtype probe ----------
// int64 with values < 2^17 -> all odd 32-bit words are 0. int32 random ids -> virtually never.
__global__ __launch_bounds__(256) void k_detect(const unsigned int* __restrict__ ei, int* __restrict__ flag) {
  __shared__ int nz;
  if (threadIdx.x == 0) nz = 0;
  __syncthreads();
  if (ei[threadIdx.x * 2 + 1] != 0u) atomicAdd(&nz, 1);
  __syncthreads();
  if (threadIdx.x == 0) flag[0] = (nz == 0) ? 1 : 0;
}

__device__ inline int load_idx(const void* ei, long long i, int is64) {
  return is64 ? (int)((const long long*)ei)[i] : ((const int*)ei)[i];
}

// ---------- CSR build ----------
__global__ __launch_bounds__(256) void k_init_counts(int* __restrict__ counts) {
  int i = blockIdx.x * 256 + threadIdx.x;
  if (i < NN) counts[i * PAD] = 1;  // self-loop
}

__global__ __launch_bounds__(256) void k_count(const void* __restrict__ ei, const int* __restrict__ flag,
                                               int* __restrict__ counts) {
  int is64 = flag[0];
  int base = blockIdx.x * 256 * EPT + threadIdx.x;
  #pragma unroll
  for (int k = 0; k < EPT; k++) {
    int e = base + k * 256;
    if (e < NE) atomicAdd(&counts[load_idx(ei, (long long)NE + e, is64) * PAD], 1);
  }
}

__global__ __launch_bounds__(256) void k_block_reduce(const int* __restrict__ counts, int* __restrict__ blockSums) {
  __shared__ int s[256];
  int i = blockIdx.x * 256 + threadIdx.x;
  s[threadIdx.x] = (i < NN) ? counts[i * PAD] : 0;
  __syncthreads();
  for (int off = 128; off > 0; off >>= 1) {
    if (threadIdx.x < off) s[threadIdx.x] += s[threadIdx.x + off];
    __syncthreads();
  }
  if (threadIdx.x == 0) blockSums[blockIdx.x] = s[0];
}

__global__ __launch_bounds__(512) void k_scan_top(int* __restrict__ blockSums, int* __restrict__ row_start, int nblk) {
  __shared__ int s[512];
  int t = threadIdx.x;
  int v = (t < nblk) ? blockSums[t] : 0;
  s[t] = v;
  __syncthreads();
  for (int off = 1; off < 512; off <<= 1) {
    int u = (t >= off) ? s[t - off] : 0;
    __syncthreads();
    s[t] += u;
    __syncthreads();
  }
  if (t < nblk) blockSums[t] = s[t] - v;  // exclusive block offsets, in place
  if (t == 0) row_start[NN] = TOT;
}

// counts and cursor share one (padded) buffer: read count, then overwrite with fill cursor.
__global__ __launch_bounds__(256) void k_scan_fill(const int* __restrict__ blockOff,
                                                   int* __restrict__ cnt_cur,
                                                   int* __restrict__ row_start,
                                                   float* __restrict__ dinv, int* __restrict__ csr_src) {
  __shared__ int s[256];
  int i = blockIdx.x * 256 + threadIdx.x;
  int c = (i < NN) ? cnt_cur[i * PAD] : 0;
  s[threadIdx.x] = c;
  __syncthreads();
  for (int off = 1; off < 256; off <<= 1) {
    int u = (threadIdx.x >= off) ? s[threadIdx.x - off] : 0;
    __syncthreads();
    s[threadIdx.x] += u;
    __syncthreads();
  }
  if (i < NN) {
    int start = blockOff[blockIdx.x] + s[threadIdx.x] - c;  // exclusive scan
    row_start[i]  = start;
    cnt_cur[i * PAD] = start + 1;    // cursor; slot 0 holds the self-loop
    csr_src[start] = i;
    dinv[i] = rsqrtf((float)c);      // deg includes self-loop, >= 1
  }
}

__global__ __launch_bounds__(256) void k_fill(const void* __restrict__ ei, const int* __restrict__ flag,
                                              int* __restrict__ cursor, int* __restrict__ csr_src) {
  int is64 = flag[0];
  int base = blockIdx.x * 256 * EPT + threadIdx.x;
  #pragma unroll
  for (int k = 0; k < EPT; k++) {
    int e = base + k * 256;
    if (e < NE) {
      int sidx = load_idx(ei, e, is64);
      int d    = load_idx(ei, (long long)NE + e, is64);
      int p = atomicAdd(&cursor[d * PAD], 1);
      csr_src[p] = sidx;
    }
  }
}

// ---------- fp32-accum GEMM: Y[N,OUTC] = X[N,128] @ W[128,OUTC]; X/Y fp32 or fp16 ----------
template<int OUTC, bool IN_H, bool OUT_H>
__global__ __launch_bounds__(256) void k_gemm(const void* __restrict__ Xv,
                                              const float* __restrict__ W,
                                              void* __restrict__ Yv, int nrows) {
  constexpr int CG   = OUTC / 8;   // col groups of 8
  constexpr int RG   = 256 / CG;   // row groups of 4
  constexpr int ROWS = RG * 4;     // rows per block
  constexpr int KB   = 64;         // k-chunk
  constexpr int XS   = 65;         // padded LDS stride
  __shared__ float sW[KB * OUTC];
  __shared__ float sX[ROWS * XS];
  const int tid  = threadIdx.x;
  const int row0 = blockIdx.x * ROWS;
  const int cg = tid % CG, rg = tid / CG;
  float acc[4][8] = {};

  for (int kc = 0; kc < 128; kc += KB) {
    __syncthreads();
    for (int i = tid * 4; i < KB * OUTC; i += 1024)
      *(float4*)&sW[i] = *(const float4*)&W[kc * OUTC + i];
    if constexpr (!IN_H) {
      const float* X = (const float*)Xv;
      for (int idx = tid; idx < ROWS * (KB / 4); idx += 256) {
        int r = idx / (KB / 4), k4 = idx % (KB / 4);
        int gr = row0 + r;
        float4 v = make_float4(0.f, 0.f, 0.f, 0.f);
        if (gr < nrows) v = *(const float4*)&X[(size_t)gr * 128 + kc + k4 * 4];
        float* p = &sX[r * XS + k4 * 4];
        p[0] = v.x; p[1] = v.y; p[2] = v.z; p[3] = v.w;
      }
    } else {
      const unsigned short* X = (const unsigned short*)Xv;
      for (int idx = tid; idx < ROWS * (KB / 8); idx += 256) {
        int r = idx / (KB / 8), g = idx % (KB / 8);
        int gr = row0 + r;
        uint4 v = make_uint4(0u, 0u, 0u, 0u);
        if (gr < nrows) v = *(const uint4*)&X[(size_t)gr * 128 + kc + g * 8];
        float* p = &sX[r * XS + g * 8];
        float2 f;
        f = h2f2(v.x); p[0] = f.x; p[1] = f.y;
        f = h2f2(v.y); p[2] = f.x; p[3] = f.y;
        f = h2f2(v.z); p[4] = f.x; p[5] = f.y;
        f = h2f2(v.w); p[6] = f.x; p[7] = f.y;
      }
    }
    __syncthreads();
    #pragma unroll 8
    for (int k = 0; k < KB; k++) {
      float aa[4];
      aa[0] = sX[(rg * 4 + 0) * XS + k];
      aa[1] = sX[(rg * 4 + 1) * XS + k];
      aa[2] = sX[(rg * 4 + 2) * XS + k];
      aa[3] = sX[(rg * 4 + 3) * XS + k];
      float4 b0 = *(const float4*)&sW[k * OUTC + cg * 8];
      float4 b1 = *(const float4*)&sW[k * OUTC + cg * 8 + 4];
      float bb[8] = {b0.x, b0.y, b0.z, b0.w, b1.x, b1.y, b1.z, b1.w};
      #pragma unroll
      for (int i2 = 0; i2 < 4; i2++)
        #pragma unroll
        for (int j2 = 0; j2 < 8; j2++)
          acc[i2][j2] = fmaf(aa[i2], bb[j2], acc[i2][j2]);
    }
  }
  #pragma unroll
  for (int i2 = 0; i2 < 4; i2++) {
    int gr = row0 + rg * 4 + i2;
    if (gr < nrows) {
      if constexpr (OUT_H) {
        unsigned short* Y = (unsigned short*)Yv;
        uint4 o;
        o.x = f2h2(acc[i2][0], acc[i2][1]);
        o.y = f2h2(acc[i2][2], acc[i2][3]);
        o.z = f2h2(acc[i2][4], acc[i2][5]);
        o.w = f2h2(acc[i2][6], acc[i2][7]);
        *(uint4*)&Y[(size_t)gr * OUTC + cg * 8] = o;
      } else {
        float* Y = (float*)Yv;
        *(float4*)&Y[(size_t)gr * OUTC + cg * 8]     = make_float4(acc[i2][0], acc[i2][1], acc[i2][2], acc[i2][3]);
        *(float4*)&Y[(size_t)gr * OUTC + cg * 8 + 4] = make_float4(acc[i2][4], acc[i2][5], acc[i2][6], acc[i2][7]);
      }
    }
  }
}

// ---------- aggregation: out[n] = dinv[n] * sum_{s in CSR(n)} dinv[s]*h[s] + b ----------
// input h always fp16; output fp16 (mid-layer) or fp32 (final).
template<int F, bool RELU, bool OUT_H>
__global__ __launch_bounds__(256) void k_agg(const unsigned short* __restrict__ h, const float* __restrict__ dinv,
                                             const int* __restrict__ row_start, const int* __restrict__ csr_src,
                                             const float* __restrict__ bias, void* __restrict__ outv) {
  constexpr int LPN = F / 8;       // lanes per node (uint4 = 8 halves each)
  constexpr int NPB = 256 / LPN;   // nodes per block
  int node = blockIdx.x * NPB + threadIdx.x / LPN;
  int lane = threadIdx.x % LPN;
  if (node >= NN) return;
  int j0 = row_start[node], j1 = row_start[node + 1];
  float acc[8] = {};
  #pragma unroll 2
  for (int j = j0; j < j1; j++) {
    int s = csr_src[j];
    float w = dinv[s];
    uint4 v = *(const uint4*)&h[(size_t)s * F + lane * 8];
    float2 f;
    f = h2f2(v.x); acc[0] = fmaf(w, f.x, acc[0]); acc[1] = fmaf(w, f.y, acc[1]);
    f = h2f2(v.y); acc[2] = fmaf(w, f.x, acc[2]); acc[3] = fmaf(w, f.y, acc[3]);
    f = h2f2(v.z); acc[4] = fmaf(w, f.x, acc[4]); acc[5] = fmaf(w, f.y, acc[5]);
    f = h2f2(v.w); acc[6] = fmaf(w, f.x, acc[6]); acc[7] = fmaf(w, f.y, acc[7]);
  }
  float dn = dinv[node];
  float o[8];
  #pragma unroll
  for (int t = 0; t < 8; t++) {
    o[t] = fmaf(dn, acc[t], bias[lane * 8 + t]);
    if (RELU) o[t] = fmaxf(o[t], 0.f);
  }
  if constexpr (OUT_H) {
    unsigned short* out = (unsigned short*)outv;
    uint4 w;
    w.x = f2h2(o[0], o[1]);
    w.y = f2h2(o[2], o[3]);
    w.z = f2h2(o[4], o[5]);
    w.w = f2h2(o[6], o[7]);
    *(uint4*)&out[(size_t)node * F + lane * 8] = w;
  } else {
    float* out = (float*)outv;
    *(float4*)&out[(size_t)node * F + lane * 8]     = make_float4(o[0], o[1], o[2], o[3]);
    *(float4*)&out[(size_t)node * F + lane * 8 + 4] = make_float4(o[4], o[5], o[6], o[7]);
  }
}

// ---------- launch ----------
extern "C" void kernel_launch(void* const* d_in, const int* in_sizes, int n_in,
                              void* d_out, int out_size, void* d_ws, size_t ws_size,
                              hipStream_t stream) {
  const float* x  = (const float*)d_in[0];
  const void*  ei = d_in[1];
  const float* W1 = (const float*)d_in[2];
  const float* b1 = (const float*)d_in[3];
  const float* W2 = (const float*)d_in[4];
  const float* b2 = (const float*)d_in[5];
  float* out = (float*)d_out;

  char* ws = (char*)d_ws;
  size_t off = 0;
  auto wsalloc = [&](size_t bytes) -> void* {
    void* p = ws + off;
    off += (bytes + 255) & ~(size_t)255;
    return p;
  };
  int*            row_start = (int*)   wsalloc((NN + 1) * sizeof(int));
  int*            cnt_cur   = (int*)   wsalloc((size_t)NN * PAD * sizeof(int));  // 6.4 MB padded
  int*            blockSums = (int*)   wsalloc(512 * sizeof(int));
  float*          dinv      = (float*) wsalloc(NN * sizeof(float));
  int*            flag      = (int*)   wsalloc(64);
  int*            csr_src   = (int*)   wsalloc((size_t)TOT * sizeof(int));
  unsigned short* h1        = (unsigned short*)wsalloc((size_t)NN * 128 * sizeof(unsigned short));
  unsigned short* hmid      = (unsigned short*)wsalloc((size_t)NN * 128 * sizeof(unsigned short));
  unsigned short* hL2       = h1;  // [N,64] fp16 reuses h1 (dead by then)
  // total ws: ~65 MB (known available: >=116 MB from round-3 f32 path)

  constexpr int NBLK = (NN + 255) / 256;            // 391
  constexpr int EBLK = (NE + 256 * EPT - 1) / (256 * EPT);  // 1563

  k_detect<<<1, 256, 0, stream>>>((const unsigned int*)ei, flag);
  k_init_counts<<<NBLK, 256, 0, stream>>>(cnt_cur);
  k_count<<<EBLK, 256, 0, stream>>>(ei, flag, cnt_cur);
  k_block_reduce<<<NBLK, 256, 0, stream>>>(cnt_cur, blockSums);
  k_scan_top<<<1, 512, 0, stream>>>(blockSums, row_start, NBLK);
  k_scan_fill<<<NBLK, 256, 0, stream>>>(blockSums, cnt_cur, row_start, dinv, csr_src);
  k_fill<<<EBLK, 256, 0, stream>>>(ei, flag, cnt_cur, csr_src);

  k_gemm<128, false, true><<<(NN + 63) / 64, 256, 0, stream>>>(x, W1, h1, NN);
  k_agg<128, true, true><<<(NN + 15) / 16, 256, 0, stream>>>(h1, dinv, row_start, csr_src, b1, hmid);
  k_gemm<64, true, true><<<(NN + 127) / 128, 256, 0, stream>>>(hmid, W2, hL2, NN);
  k_agg<64, false, false><<<(NN + 31) / 32, 256, 0, stream>>>(hL2, dinv, row_start, csr_src, b2, out);
}

// Round 5
// 327.865 us; speedup vs baseline: 1.8039x; 1.4882x over previous
//
#include <hip/hip_runtime.h>
#include <hip/hip_fp16.h>

constexpr int NN  = 100000;
constexpr int NE  = 1600000;
constexpr int TOT = NE + NN;

constexpr int NBUK    = (NN + 255) / 256;   // 391 buckets of 256 nodes (by dst>>8)
constexpr int EBLOCKS = 512;                // blocks for hist/scatter passes
constexpr int EPB     = NE / EBLOCKS;       // 3125 edges per block (exact)

// ---------- fp16 helpers ----------
__device__ inline float2 h2f2(unsigned int u) {
  __half2 h = __builtin_bit_cast(__half2, u);
  return __half22float2(h);
}
__device__ inline unsigned int f2h2(float a, float b) {
  __half2 h = __floats2half2_rn(a, b);
  return __builtin_bit_cast(unsigned int, h);
}

// ---------- edge_index dtype probe ----------
// int64 with values < 2^17 -> all odd 32-bit words are 0. int32 random ids -> virtually never.
__global__ __launch_bounds__(256) void k_detect(const unsigned int* __restrict__ ei, int* __restrict__ flag) {
  __shared__ int nz;
  if (threadIdx.x == 0) nz = 0;
  __syncthreads();
  if (ei[threadIdx.x * 2 + 1] != 0u) atomicAdd(&nz, 1);
  __syncthreads();
  if (threadIdx.x == 0) flag[0] = (nz == 0) ? 1 : 0;
}

__device__ inline int load_idx(const void* ei, long long i, int is64) {
  return is64 ? (int)((const long long*)ei)[i] : ((const int*)ei)[i];
}

// ---------- bucketed CSR build (no global atomics) ----------

// Pass 1: per-block histogram over dst buckets.  hist_g[b*EBLOCKS + blk]
__global__ __launch_bounds__(256) void k_hist(const void* __restrict__ ei, const int* __restrict__ flag,
                                              int* __restrict__ hist_g) {
  __shared__ int h[NBUK];
  int is64 = flag[0];
  for (int i = threadIdx.x; i < NBUK; i += 256) h[i] = 0;
  __syncthreads();
  int e0 = blockIdx.x * EPB;
  for (int e = e0 + threadIdx.x; e < e0 + EPB; e += 256) {
    int d = load_idx(ei, (long long)NE + e, is64);
    atomicAdd(&h[d >> 8], 1);
  }
  __syncthreads();
  for (int i = threadIdx.x; i < NBUK; i += 256)
    hist_g[i * EBLOCKS + blockIdx.x] = h[i];
}

// Pass 2a: within each bucket, exclusive scan across the EBLOCKS blocks.
__global__ __launch_bounds__(512) void k_scan_hist(int* __restrict__ hist_g, int* __restrict__ bucket_total) {
  __shared__ int s[EBLOCKS];
  int b = blockIdx.x, t = threadIdx.x;
  int v = hist_g[b * EBLOCKS + t];
  s[t] = v;
  __syncthreads();
  for (int off = 1; off < EBLOCKS; off <<= 1) {
    int u = (t >= off) ? s[t - off] : 0;
    __syncthreads();
    s[t] += u;
    __syncthreads();
  }
  hist_g[b * EBLOCKS + t] = s[t] - v;  // exclusive prefix within bucket
  if (t == EBLOCKS - 1) bucket_total[b] = s[t];
}

// Pass 2b: scan bucket totals -> edge_base[0..NBUK]; also sentinel row_start[NN].
__global__ __launch_bounds__(512) void k_scan_buckets(const int* __restrict__ bucket_total,
                                                      int* __restrict__ edge_base, int* __restrict__ row_start) {
  __shared__ int s[512];
  int t = threadIdx.x;
  int v = (t < NBUK) ? bucket_total[t] : 0;
  s[t] = v;
  __syncthreads();
  for (int off = 1; off < 512; off <<= 1) {
    int u = (t >= off) ? s[t - off] : 0;
    __syncthreads();
    s[t] += u;
    __syncthreads();
  }
  if (t <= NBUK) edge_base[t] = s[t] - v;  // exclusive; t==NBUK gives NE
  if (t == 0) row_start[NN] = TOT;
}

// Pass 3: scatter (src,dst) records into per-(bucket,block) contiguous chunks. LDS cursors only.
__global__ __launch_bounds__(256) void k_scatter(const void* __restrict__ ei, const int* __restrict__ flag,
                                                 const int* __restrict__ hist_g, const int* __restrict__ edge_base,
                                                 int2* __restrict__ rec) {
  __shared__ int cur[NBUK];
  int is64 = flag[0];
  for (int i = threadIdx.x; i < NBUK; i += 256)
    cur[i] = edge_base[i] + hist_g[i * EBLOCKS + blockIdx.x];
  __syncthreads();
  int e0 = blockIdx.x * EPB;
  for (int e = e0 + threadIdx.x; e < e0 + EPB; e += 256) {
    int sA = load_idx(ei, e, is64);
    int d  = load_idx(ei, (long long)NE + e, is64);
    int p = atomicAdd(&cur[d >> 8], 1);
    rec[p] = make_int2(sA, d);
  }
}

// Pass 4: one block per bucket -> per-node counts, row_start, dinv, csr_src (all LDS-local placement).
__global__ __launch_bounds__(256) void k_bucket_csr(const int2* __restrict__ rec, const int* __restrict__ edge_base,
                                                    int* __restrict__ row_start, float* __restrict__ dinv,
                                                    int* __restrict__ csr_src) {
  __shared__ int cnt[256];
  __shared__ int s[256];
  int b = blockIdx.x, t = threadIdx.x;
  int node = b * 256 + t;
  cnt[t] = 0;
  __syncthreads();
  int j0 = edge_base[b], j1 = edge_base[b + 1];
  for (int j = j0 + t; j < j1; j += 256)
    atomicAdd(&cnt[rec[j].y & 255], 1);
  __syncthreads();
  int c = (node < NN) ? cnt[t] + 1 : 0;  // +1 self-loop
  s[t] = c;
  __syncthreads();
  for (int off = 1; off < 256; off <<= 1) {
    int u = (t >= off) ? s[t - off] : 0;
    __syncthreads();
    s[t] += u;
    __syncthreads();
  }
  int csr_b = j0 + b * 256;             // bucket's csr base (256 self-loops per preceding bucket)
  int start = csr_b + s[t] - c;         // exclusive
  if (node < NN) {
    row_start[node] = start;
    dinv[node] = rsqrtf((float)c);
    csr_src[start] = node;              // self-loop in slot 0
  }
  __syncthreads();
  cnt[t] = start + 1;                    // reuse as cursor
  __syncthreads();
  for (int j = j0 + t; j < j1; j += 256) {
    int2 r = rec[j];
    int p = atomicAdd(&cnt[r.y & 255], 1);
    csr_src[p] = r.x;
  }
}

// ---------- fp32-accum GEMM: Y[N,OUTC] = X[N,128] @ W[128,OUTC]; X/Y fp32 or fp16 ----------
template<int OUTC, bool IN_H, bool OUT_H>
__global__ __launch_bounds__(256) void k_gemm(const void* __restrict__ Xv,
                                              const float* __restrict__ W,
                                              void* __restrict__ Yv, int nrows) {
  constexpr int CG   = OUTC / 8;
  constexpr int RG   = 256 / CG;
  constexpr int ROWS = RG * 4;
  constexpr int KB   = 64;
  constexpr int XS   = 65;
  __shared__ float sW[KB * OUTC];
  __shared__ float sX[ROWS * XS];
  const int tid  = threadIdx.x;
  const int row0 = blockIdx.x * ROWS;
  const int cg = tid % CG, rg = tid / CG;
  float acc[4][8] = {};

  for (int kc = 0; kc < 128; kc += KB) {
    __syncthreads();
    for (int i = tid * 4; i < KB * OUTC; i += 1024)
      *(float4*)&sW[i] = *(const float4*)&W[kc * OUTC + i];
    if constexpr (!IN_H) {
      const float* X = (const float*)Xv;
      for (int idx = tid; idx < ROWS * (KB / 4); idx += 256) {
        int r = idx / (KB / 4), k4 = idx % (KB / 4);
        int gr = row0 + r;
        float4 v = make_float4(0.f, 0.f, 0.f, 0.f);
        if (gr < nrows) v = *(const float4*)&X[(size_t)gr * 128 + kc + k4 * 4];
        float* p = &sX[r * XS + k4 * 4];
        p[0] = v.x; p[1] = v.y; p[2] = v.z; p[3] = v.w;
      }
    } else {
      const unsigned short* X = (const unsigned short*)Xv;
      for (int idx = tid; idx < ROWS * (KB / 8); idx += 256) {
        int r = idx / (KB / 8), g = idx % (KB / 8);
        int gr = row0 + r;
        uint4 v = make_uint4(0u, 0u, 0u, 0u);
        if (gr < nrows) v = *(const uint4*)&X[(size_t)gr * 128 + kc + g * 8];
        float* p = &sX[r * XS + g * 8];
        float2 f;
        f = h2f2(v.x); p[0] = f.x; p[1] = f.y;
        f = h2f2(v.y); p[2] = f.x; p[3] = f.y;
        f = h2f2(v.z); p[4] = f.x; p[5] = f.y;
        f = h2f2(v.w); p[6] = f.x; p[7] = f.y;
      }
    }
    __syncthreads();
    #pragma unroll 8
    for (int k = 0; k < KB; k++) {
      float aa[4];
      aa[0] = sX[(rg * 4 + 0) * XS + k];
      aa[1] = sX[(rg * 4 + 1) * XS + k];
      aa[2] = sX[(rg * 4 + 2) * XS + k];
      aa[3] = sX[(rg * 4 + 3) * XS + k];
      float4 b0 = *(const float4*)&sW[k * OUTC + cg * 8];
      float4 b1 = *(const float4*)&sW[k * OUTC + cg * 8 + 4];
      float bb[8] = {b0.x, b0.y, b0.z, b0.w, b1.x, b1.y, b1.z, b1.w};
      #pragma unroll
      for (int i2 = 0; i2 < 4; i2++)
        #pragma unroll
        for (int j2 = 0; j2 < 8; j2++)
          acc[i2][j2] = fmaf(aa[i2], bb[j2], acc[i2][j2]);
    }
  }
  #pragma unroll
  for (int i2 = 0; i2 < 4; i2++) {
    int gr = row0 + rg * 4 + i2;
    if (gr < nrows) {
      if constexpr (OUT_H) {
        unsigned short* Y = (unsigned short*)Yv;
        uint4 o;
        o.x = f2h2(acc[i2][0], acc[i2][1]);
        o.y = f2h2(acc[i2][2], acc[i2][3]);
        o.z = f2h2(acc[i2][4], acc[i2][5]);
        o.w = f2h2(acc[i2][6], acc[i2][7]);
        *(uint4*)&Y[(size_t)gr * OUTC + cg * 8] = o;
      } else {
        float* Y = (float*)Yv;
        *(float4*)&Y[(size_t)gr * OUTC + cg * 8]     = make_float4(acc[i2][0], acc[i2][1], acc[i2][2], acc[i2][3]);
        *(float4*)&Y[(size_t)gr * OUTC + cg * 8 + 4] = make_float4(acc[i2][4], acc[i2][5], acc[i2][6], acc[i2][7]);
      }
    }
  }
}

// ---------- aggregation: out[n] = dinv[n] * sum_{s in CSR(n)} dinv[s]*h[s] + b ----------
template<int F, bool RELU, bool OUT_H>
__global__ __launch_bounds__(256) void k_agg(const unsigned short* __restrict__ h, const float* __restrict__ dinv,
                                             const int* __restrict__ row_start, const int* __restrict__ csr_src,
                                             const float* __restrict__ bias, void* __restrict__ outv) {
  constexpr int LPN = F / 8;
  constexpr int NPB = 256 / LPN;
  int node = blockIdx.x * NPB + threadIdx.x / LPN;
  int lane = threadIdx.x % LPN;
  if (node >= NN) return;
  int j0 = row_start[node], j1 = row_start[node + 1];
  float acc[8] = {};
  #pragma unroll 2
  for (int j = j0; j < j1; j++) {
    int s = csr_src[j];
    float w = dinv[s];
    uint4 v = *(const uint4*)&h[(size_t)s * F + lane * 8];
    float2 f;
    f = h2f2(v.x); acc[0] = fmaf(w, f.x, acc[0]); acc[1] = fmaf(w, f.y, acc[1]);
    f = h2f2(v.y); acc[2] = fmaf(w, f.x, acc[2]); acc[3] = fmaf(w, f.y, acc[3]);
    f = h2f2(v.z); acc[4] = fmaf(w, f.x, acc[4]); acc[5] = fmaf(w, f.y, acc[5]);
    f = h2f2(v.w); acc[6] = fmaf(w, f.x, acc[6]); acc[7] = fmaf(w, f.y, acc[7]);
  }
  float dn = dinv[node];
  float o[8];
  #pragma unroll
  for (int t = 0; t < 8; t++) {
    o[t] = fmaf(dn, acc[t], bias[lane * 8 + t]);
    if (RELU) o[t] = fmaxf(o[t], 0.f);
  }
  if constexpr (OUT_H) {
    unsigned short* out = (unsigned short*)outv;
    uint4 w;
    w.x = f2h2(o[0], o[1]);
    w.y = f2h2(o[2], o[3]);
    w.z = f2h2(o[4], o[5]);
    w.w = f2h2(o[6], o[7]);
    *(uint4*)&out[(size_t)node * F + lane * 8] = w;
  } else {
    float* out = (float*)outv;
    *(float4*)&out[(size_t)node * F + lane * 8]     = make_float4(o[0], o[1], o[2], o[3]);
    *(float4*)&out[(size_t)node * F + lane * 8 + 4] = make_float4(o[4], o[5], o[6], o[7]);
  }
}

// ---------- launch ----------
extern "C" void kernel_launch(void* const* d_in, const int* in_sizes, int n_in,
                              void* d_out, int out_size, void* d_ws, size_t ws_size,
                              hipStream_t stream) {
  const float* x  = (const float*)d_in[0];
  const void*  ei = d_in[1];
  const float* W1 = (const float*)d_in[2];
  const float* b1 = (const float*)d_in[3];
  const float* W2 = (const float*)d_in[4];
  const float* b2 = (const float*)d_in[5];
  float* out = (float*)d_out;

  char* ws = (char*)d_ws;
  size_t off = 0;
  auto wsalloc = [&](size_t bytes) -> void* {
    void* p = ws + off;
    off += (bytes + 255) & ~(size_t)255;
    return p;
  };
  int*            row_start    = (int*)   wsalloc((NN + 1) * sizeof(int));
  int*            hist_g       = (int*)   wsalloc((size_t)NBUK * EBLOCKS * sizeof(int)); // 0.8 MB
  int*            bucket_total = (int*)   wsalloc(NBUK * sizeof(int));
  int*            edge_base    = (int*)   wsalloc((NBUK + 1) * sizeof(int));
  float*          dinv         = (float*) wsalloc(NN * sizeof(float));
  int*            flag         = (int*)   wsalloc(64);
  int2*           rec          = (int2*)  wsalloc((size_t)NE * sizeof(int2));   // 12.8 MB
  int*            csr_src      = (int*)   wsalloc((size_t)TOT * sizeof(int));   // 6.8 MB
  unsigned short* h1           = (unsigned short*)wsalloc((size_t)NN * 128 * sizeof(unsigned short));
  unsigned short* hmid         = (unsigned short*)wsalloc((size_t)NN * 128 * sizeof(unsigned short));
  unsigned short* hL2          = h1;  // [N,64] fp16 reuses h1 (dead by then)
  // total ws ~ 73 MB (>=116 MB known available)

  k_detect<<<1, 256, 0, stream>>>((const unsigned int*)ei, flag);
  k_hist<<<EBLOCKS, 256, 0, stream>>>(ei, flag, hist_g);
  k_scan_hist<<<NBUK, EBLOCKS, 0, stream>>>(hist_g, bucket_total);
  k_scan_buckets<<<1, 512, 0, stream>>>(bucket_total, edge_base, row_start);
  k_scatter<<<EBLOCKS, 256, 0, stream>>>(ei, flag, hist_g, edge_base, rec);
  k_bucket_csr<<<NBUK, 256, 0, stream>>>(rec, edge_base, row_start, dinv, csr_src);

  k_gemm<128, false, true><<<(NN + 63) / 64, 256, 0, stream>>>(x, W1, h1, NN);
  k_agg<128, true, true><<<(NN + 15) / 16, 256, 0, stream>>>(h1, dinv, row_start, csr_src, b1, hmid);
  k_gemm<64, true, true><<<(NN + 127) / 128, 256, 0, stream>>>(hmid, W2, hL2, NN);
  k_agg<64, false, false><<<(NN + 31) / 32, 256, 0, stream>>>(hL2, dinv, row_start, csr_src, b2, out);
}

// Round 7
// 291.544 us; speedup vs baseline: 2.0286x; 1.1246x over previous
//
#include <hip/hip_runtime.h>
#include <hip/hip_fp16.h>

constexpr int NN  = 100000;
constexpr int NE  = 1600000;
constexpr int TOT = NE + NN;

constexpr int NBUK    = (NN + 255) / 256;   // 391 buckets of 256 nodes (by dst>>8)
constexpr int EBLOCKS = 512;                // blocks for hist/scatter passes
constexpr int EPB     = NE / EBLOCKS;       // 3125 edges per block (exact)

typedef _Float16 f16x8 __attribute__((ext_vector_type(8)));
typedef float    f32x4 __attribute__((ext_vector_type(4)));

// ---------- fp16 helpers ----------
__device__ inline float2 h2f2(unsigned int u) {
  __half2 h = __builtin_bit_cast(__half2, u);
  return __half22float2(h);
}
__device__ inline unsigned int f2h2(float a, float b) {
  __half2 h = __floats2half2_rn(a, b);
  return __builtin_bit_cast(unsigned int, h);
}

// ---------- edge_index dtype probe ----------
__global__ __launch_bounds__(256) void k_detect(const unsigned int* __restrict__ ei, int* __restrict__ flag) {
  __shared__ int nz;
  if (threadIdx.x == 0) nz = 0;
  __syncthreads();
  if (ei[threadIdx.x * 2 + 1] != 0u) atomicAdd(&nz, 1);
  __syncthreads();
  if (threadIdx.x == 0) flag[0] = (nz == 0) ? 1 : 0;
}

__device__ inline int load_idx(const void* ei, long long i, int is64) {
  return is64 ? (int)((const long long*)ei)[i] : ((const int*)ei)[i];
}

// ---------- bucketed CSR build (no global atomics) ----------

__global__ __launch_bounds__(256) void k_hist(const void* __restrict__ ei, const int* __restrict__ flag,
                                              int* __restrict__ hist_g) {
  __shared__ int h[NBUK];
  int is64 = flag[0];
  for (int i = threadIdx.x; i < NBUK; i += 256) h[i] = 0;
  __syncthreads();
  int e0 = blockIdx.x * EPB;
  for (int e = e0 + threadIdx.x; e < e0 + EPB; e += 256) {
    int d = load_idx(ei, (long long)NE + e, is64);
    atomicAdd(&h[d >> 8], 1);
  }
  __syncthreads();
  for (int i = threadIdx.x; i < NBUK; i += 256)
    hist_g[i * EBLOCKS + blockIdx.x] = h[i];
}

__global__ __launch_bounds__(512) void k_scan_hist(int* __restrict__ hist_g, int* __restrict__ bucket_total) {
  __shared__ int s[EBLOCKS];
  int b = blockIdx.x, t = threadIdx.x;
  int v = hist_g[b * EBLOCKS + t];
  s[t] = v;
  __syncthreads();
  for (int off = 1; off < EBLOCKS; off <<= 1) {
    int u = (t >= off) ? s[t - off] : 0;
    __syncthreads();
    s[t] += u;
    __syncthreads();
  }
  hist_g[b * EBLOCKS + t] = s[t] - v;
  if (t == EBLOCKS - 1) bucket_total[b] = s[t];
}

__global__ __launch_bounds__(512) void k_scan_buckets(const int* __restrict__ bucket_total,
                                                      int* __restrict__ edge_base, int* __restrict__ row_start) {
  __shared__ int s[512];
  int t = threadIdx.x;
  int v = (t < NBUK) ? bucket_total[t] : 0;
  s[t] = v;
  __syncthreads();
  for (int off = 1; off < 512; off <<= 1) {
    int u = (t >= off) ? s[t - off] : 0;
    __syncthreads();
    s[t] += u;
    __syncthreads();
  }
  if (t <= NBUK) edge_base[t] = s[t] - v;
  if (t == 0) row_start[NN] = TOT;
}

__global__ __launch_bounds__(256) void k_scatter(const void* __restrict__ ei, const int* __restrict__ flag,
                                                 const int* __restrict__ hist_g, const int* __restrict__ edge_base,
                                                 int2* __restrict__ rec) {
  __shared__ int cur[NBUK];
  int is64 = flag[0];
  for (int i = threadIdx.x; i < NBUK; i += 256)
    cur[i] = edge_base[i] + hist_g[i * EBLOCKS + blockIdx.x];
  __syncthreads();
  int e0 = blockIdx.x * EPB;
  for (int e = e0 + threadIdx.x; e < e0 + EPB; e += 256) {
    int sA = load_idx(ei, e, is64);
    int d  = load_idx(ei, (long long)NE + e, is64);
    int p = atomicAdd(&cur[d >> 8], 1);
    rec[p] = make_int2(sA, d);
  }
}

__global__ __launch_bounds__(256) void k_bucket_csr(const int2* __restrict__ rec, const int* __restrict__ edge_base,
                                                    int* __restrict__ row_start, float* __restrict__ dinv,
                                                    int* __restrict__ csr_src) {
  __shared__ int cnt[256];
  __shared__ int s[256];
  int b = blockIdx.x, t = threadIdx.x;
  int node = b * 256 + t;
  cnt[t] = 0;
  __syncthreads();
  int j0 = edge_base[b], j1 = edge_base[b + 1];
  for (int j = j0 + t; j < j1; j += 256)
    atomicAdd(&cnt[rec[j].y & 255], 1);
  __syncthreads();
  int c = (node < NN) ? cnt[t] + 1 : 0;  // +1 self-loop
  s[t] = c;
  __syncthreads();
  for (int off = 1; off < 256; off <<= 1) {
    int u = (t >= off) ? s[t - off] : 0;
    __syncthreads();
    s[t] += u;
    __syncthreads();
  }
  int csr_b = j0 + b * 256;
  int start = csr_b + s[t] - c;
  if (node < NN) {
    row_start[node] = start;
    dinv[node] = rsqrtf((float)c);
    csr_src[start] = node;              // self-loop in slot 0
  }
  __syncthreads();
  cnt[t] = start + 1;                   // reuse as cursor
  __syncthreads();
  for (int j = j0 + t; j < j1; j += 256) {
    int2 r = rec[j];
    int p = atomicAdd(&cnt[r.y & 255], 1);
    csr_src[p] = r.x;
  }
}

// ---------- MFMA fp16 GEMM: Y[r] = dinv[r] * (X[r] @ W), Y fp16 ----------
// X: [N,128] fp32 (IN_H=false) or fp16 (IN_H=true); W: [128,OUTC] fp32.
// 64 rows/block, 4 waves x one 16-row strip, v_mfma_f32_16x16x32_f16.
template<int OUTC, bool IN_H>
__global__ __launch_bounds__(256) void k_gemm_mfma(const void* __restrict__ Xv,
                                                   const float* __restrict__ W,
                                                   const float* __restrict__ dinv,
                                                   unsigned short* __restrict__ Y) {
  constexpr int NT = OUTC / 16;        // col tiles: 8 or 4
  constexpr int PS = 136;              // Wt k-stride (halves), pad -> 2-way banks (free)
  constexpr int SS = OUTC + 8;         // out-stage row stride (halves), 16B-aligned rows
  constexpr int WT_H = OUTC * PS;
  constexpr int ST_H = 64 * SS;
  constexpr int SM_H = WT_H > ST_H ? WT_H : ST_H;
  __shared__ _Float16 smem[SM_H];

  const int tid  = threadIdx.x;
  const int lane = tid & 63;
  const int wv   = tid >> 6;
  const int row0 = blockIdx.x * 64;
  const int l15  = lane & 15;
  const int kg   = lane >> 4;          // 0..3

  // stage W transposed: smem[col*PS + k] = (f16)W[k][col]
  for (int idx = tid * 4; idx < 128 * OUTC; idx += 1024) {
    float4 v = *(const float4*)&W[idx];
    int k = idx / OUTC, c = idx % OUTC;
    smem[(c + 0) * PS + k] = (_Float16)v.x;
    smem[(c + 1) * PS + k] = (_Float16)v.y;
    smem[(c + 2) * PS + k] = (_Float16)v.z;
    smem[(c + 3) * PS + k] = (_Float16)v.w;
  }
  __syncthreads();

  int arow = row0 + wv * 16 + l15;
  int rr_g = arow < NN ? arow : NN - 1;   // clamp; garbage rows discarded at store

  f32x4 acc[NT];
  #pragma unroll
  for (int n = 0; n < NT; n++) acc[n] = (f32x4){0.f, 0.f, 0.f, 0.f};

  #pragma unroll
  for (int kb = 0; kb < 4; kb++) {
    int k0 = kb * 32 + kg * 8;
    f16x8 a;
    if constexpr (IN_H) {
      a = *(const f16x8*)((const _Float16*)Xv + (size_t)rr_g * 128 + k0);
    } else {
      const float* X = (const float*)Xv;
      float4 v0 = *(const float4*)&X[(size_t)rr_g * 128 + k0];
      float4 v1 = *(const float4*)&X[(size_t)rr_g * 128 + k0 + 4];
      a[0] = (_Float16)v0.x; a[1] = (_Float16)v0.y; a[2] = (_Float16)v0.z; a[3] = (_Float16)v0.w;
      a[4] = (_Float16)v1.x; a[5] = (_Float16)v1.y; a[6] = (_Float16)v1.z; a[7] = (_Float16)v1.w;
    }
    #pragma unroll
    for (int n = 0; n < NT; n++) {
      f16x8 b = *(const f16x8*)&smem[(n * 16 + l15) * PS + k0];
      acc[n] = __builtin_amdgcn_mfma_f32_16x16x32_f16(a, b, acc[n], 0, 0, 0);
    }
  }
  __syncthreads();   // all waves done reading W; reuse smem as out-stage

  // D layout: row=(lane>>4)*4+reg, col=lane&15 (HW-verified). Scale by dinv, stage.
  int rb = wv * 16 + kg * 4;           // local row base for this lane's 4 regs
  float dv[4];
  #pragma unroll
  for (int q = 0; q < 4; q++) {
    int gr = row0 + rb + q;
    dv[q] = dinv[gr < NN ? gr : NN - 1];
  }
  #pragma unroll
  for (int n = 0; n < NT; n++)
    #pragma unroll
    for (int q = 0; q < 4; q++)
      smem[(rb + q) * SS + n * 16 + l15] = (_Float16)(acc[n][q] * dv[q]);
  __syncthreads();

  // coalesced store: 16B segments
  constexpr int SEGS = OUTC / 8;       // 8 halves per 16B
  for (int u = tid; u < 64 * SEGS; u += 256) {
    int rr = u / SEGS, sg = u % SEGS;
    int gr = row0 + rr;
    if (gr < NN) {
      uint4 v = *(const uint4*)&smem[rr * SS + sg * 8];
      *(uint4*)&Y[(size_t)gr * OUTC + sg * 8] = v;
    }
  }
}

// ---------- aggregation: out[n] = dinv[n] * sum_{s in CSR(n)} h'[s] + b ----------
// h' rows are pre-scaled by dinv[s] in the GEMM epilogue -> no per-edge dinv gather.
template<int F, bool RELU, bool OUT_H>
__global__ __launch_bounds__(256) void k_agg(const unsigned short* __restrict__ h, const float* __restrict__ dinv,
                                             const int* __restrict__ row_start, const int* __restrict__ csr_src,
                                             const float* __restrict__ bias, void* __restrict__ outv) {
  constexpr int LPN = F / 8;
  constexpr int NPB = 256 / LPN;
  int node = blockIdx.x * NPB + threadIdx.x / LPN;
  int lane = threadIdx.x % LPN;
  if (node >= NN) return;
  int j0 = row_start[node], j1 = row_start[node + 1];
  float acc[8] = {};
  #pragma unroll 2
  for (int j = j0; j < j1; j++) {
    int s = csr_src[j];
    uint4 v = *(const uint4*)&h[(size_t)s * F + lane * 8];
    float2 f;
    f = h2f2(v.x); acc[0] += f.x; acc[1] += f.y;
    f = h2f2(v.y); acc[2] += f.x; acc[3] += f.y;
    f = h2f2(v.z); acc[4] += f.x; acc[5] += f.y;
    f = h2f2(v.w); acc[6] += f.x; acc[7] += f.y;
  }
  float dn = dinv[node];
  float o[8];
  #pragma unroll
  for (int t = 0; t < 8; t++) {
    o[t] = fmaf(dn, acc[t], bias[lane * 8 + t]);
    if (RELU) o[t] = fmaxf(o[t], 0.f);
  }
  if constexpr (OUT_H) {
    unsigned short* out = (unsigned short*)outv;
    uint4 w;
    w.x = f2h2(o[0], o[1]);
    w.y = f2h2(o[2], o[3]);
    w.z = f2h2(o[4], o[5]);
    w.w = f2h2(o[6], o[7]);
    *(uint4*)&out[(size_t)node * F + lane * 8] = w;
  } else {
    float* out = (float*)outv;
    *(float4*)&out[(size_t)node * F + lane * 8]     = make_float4(o[0], o[1], o[2], o[3]);
    *(float4*)&out[(size_t)node * F + lane * 8 + 4] = make_float4(o[4], o[5], o[6], o[7]);
  }
}

// ---------- launch ----------
extern "C" void kernel_launch(void* const* d_in, const int* in_sizes, int n_in,
                              void* d_out, int out_size, void* d_ws, size_t ws_size,
                              hipStream_t stream) {
  const float* x  = (const float*)d_in[0];
  const void*  ei = d_in[1];
  const float* W1 = (const float*)d_in[2];
  const float* b1 = (const float*)d_in[3];
  const float* W2 = (const float*)d_in[4];
  const float* b2 = (const float*)d_in[5];
  float* out = (float*)d_out;

  char* ws = (char*)d_ws;
  size_t off = 0;
  auto wsalloc = [&](size_t bytes) -> void* {
    void* p = ws + off;
    off += (bytes + 255) & ~(size_t)255;
    return p;
  };
  int*            row_start    = (int*)   wsalloc((NN + 1) * sizeof(int));
  int*            hist_g       = (int*)   wsalloc((size_t)NBUK * EBLOCKS * sizeof(int));
  int*            bucket_total = (int*)   wsalloc(NBUK * sizeof(int));
  int*            edge_base    = (int*)   wsalloc((NBUK + 1) * sizeof(int));
  float*          dinv         = (float*) wsalloc(NN * sizeof(float));
  int*            flag         = (int*)   wsalloc(64);
  int2*           rec          = (int2*)  wsalloc((size_t)NE * sizeof(int2));
  int*            csr_src      = (int*)   wsalloc((size_t)TOT * sizeof(int));
  unsigned short* h1           = (unsigned short*)wsalloc((size_t)NN * 128 * sizeof(unsigned short));
  unsigned short* hmid         = (unsigned short*)wsalloc((size_t)NN * 128 * sizeof(unsigned short));
  unsigned short* hL2          = h1;  // [N,64] fp16 reuses h1 (dead by then)

  k_detect<<<1, 256, 0, stream>>>((const unsigned int*)ei, flag);
  k_hist<<<EBLOCKS, 256, 0, stream>>>(ei, flag, hist_g);
  k_scan_hist<<<NBUK, EBLOCKS, 0, stream>>>(hist_g, bucket_total);
  k_scan_buckets<<<1, 512, 0, stream>>>(bucket_total, edge_base, row_start);
  k_scatter<<<EBLOCKS, 256, 0, stream>>>(ei, flag, hist_g, edge_base, rec);
  k_bucket_csr<<<NBUK, 256, 0, stream>>>(rec, edge_base, row_start, dinv, csr_src);

  constexpr int GBLK = (NN + 63) / 64;  // 1563
  k_gemm_mfma<128, false><<<GBLK, 256, 0, stream>>>(x, W1, dinv, h1);
  k_agg<128, true, true><<<(NN + 15) / 16, 256, 0, stream>>>(h1, dinv, row_start, csr_src, b1, hmid);
  k_gemm_mfma<64, true><<<GBLK, 256, 0, stream>>>(hmid, W2, dinv, hL2);
  k_agg<64, false, false><<<(NN + 31) / 32, 256, 0, stream>>>(hL2, dinv, row_start, csr_src, b2, out);
}

// Round 8
// 277.956 us; speedup vs baseline: 2.1278x; 1.0489x over previous
//
#include <hip/hip_runtime.h>
#include <hip/hip_fp16.h>

constexpr int NN  = 100000;
constexpr int NE  = 1600000;
constexpr int TOT = NE + NN;

constexpr int NBUK    = (NN + 255) / 256;   // 391 buckets of 256 nodes (by dst>>8)
constexpr int EBLOCKS = 512;                // blocks for hist/scatter passes
constexpr int EPB     = NE / EBLOCKS;       // 3125 edges per block (exact)

typedef _Float16 f16x8 __attribute__((ext_vector_type(8)));
typedef float    f32x4 __attribute__((ext_vector_type(4)));

// ---------- fp16 helpers ----------
__device__ inline float2 h2f2(unsigned int u) {
  __half2 h = __builtin_bit_cast(__half2, u);
  return __half22float2(h);
}
__device__ inline unsigned int f2h2(float a, float b) {
  __half2 h = __floats2half2_rn(a, b);
  return __builtin_bit_cast(unsigned int, h);
}

// ---------- inline edge_index dtype probe (per block, no extra kernel) ----------
// int64 with values < 2^17 -> odd 32-bit words of first 256 entries all zero.
__device__ inline int block_is64(const unsigned int* ei) {
  unsigned int w = ei[threadIdx.x * 2 + 1];
  int nz = __syncthreads_count(w != 0u);
  return nz == 0;
}

__device__ inline int load_idx(const void* ei, long long i, int is64) {
  return is64 ? (int)((const long long*)ei)[i] : ((const int*)ei)[i];
}

// ---------- bucketed CSR build (no global atomics) ----------

__global__ __launch_bounds__(256) void k_hist(const void* __restrict__ ei, int* __restrict__ hist_g) {
  __shared__ int h[NBUK];
  int is64 = block_is64((const unsigned int*)ei);
  for (int i = threadIdx.x; i < NBUK; i += 256) h[i] = 0;
  __syncthreads();
  int e0 = blockIdx.x * EPB;
  for (int e = e0 + threadIdx.x; e < e0 + EPB; e += 256) {
    int d = load_idx(ei, (long long)NE + e, is64);
    atomicAdd(&h[d >> 8], 1);
  }
  __syncthreads();
  for (int i = threadIdx.x; i < NBUK; i += 256)
    hist_g[i * EBLOCKS + blockIdx.x] = h[i];
}

__global__ __launch_bounds__(512) void k_scan_hist(int* __restrict__ hist_g, int* __restrict__ bucket_total) {
  __shared__ int s[EBLOCKS];
  int b = blockIdx.x, t = threadIdx.x;
  int v = hist_g[b * EBLOCKS + t];
  s[t] = v;
  __syncthreads();
  for (int off = 1; off < EBLOCKS; off <<= 1) {
    int u = (t >= off) ? s[t - off] : 0;
    __syncthreads();
    s[t] += u;
    __syncthreads();
  }
  hist_g[b * EBLOCKS + t] = s[t] - v;
  if (t == EBLOCKS - 1) bucket_total[b] = s[t];
}

__global__ __launch_bounds__(512) void k_scan_buckets(const int* __restrict__ bucket_total,
                                                      int* __restrict__ edge_base, int* __restrict__ row_start) {
  __shared__ int s[512];
  int t = threadIdx.x;
  int v = (t < NBUK) ? bucket_total[t] : 0;
  s[t] = v;
  __syncthreads();
  for (int off = 1; off < 512; off <<= 1) {
    int u = (t >= off) ? s[t - off] : 0;
    __syncthreads();
    s[t] += u;
    __syncthreads();
  }
  if (t <= NBUK) edge_base[t] = s[t] - v;
  if (t == 0) row_start[NN] = TOT;
}

// rec packed: (src << 8) | (dst & 255)  -- src < 2^17 fits in 24 bits.
__global__ __launch_bounds__(256) void k_scatter(const void* __restrict__ ei,
                                                 const int* __restrict__ hist_g, const int* __restrict__ edge_base,
                                                 int* __restrict__ rec) {
  __shared__ int cur[NBUK];
  int is64 = block_is64((const unsigned int*)ei);
  for (int i = threadIdx.x; i < NBUK; i += 256)
    cur[i] = edge_base[i] + hist_g[i * EBLOCKS + blockIdx.x];
  __syncthreads();
  int e0 = blockIdx.x * EPB;
  for (int e = e0 + threadIdx.x; e < e0 + EPB; e += 256) {
    int sA = load_idx(ei, e, is64);
    int d  = load_idx(ei, (long long)NE + e, is64);
    int p = atomicAdd(&cur[d >> 8], 1);
    rec[p] = (sA << 8) | (d & 255);
  }
}

__global__ __launch_bounds__(256) void k_bucket_csr(const int* __restrict__ rec, const int* __restrict__ edge_base,
                                                    int* __restrict__ row_start, float* __restrict__ dinv,
                                                    int* __restrict__ csr_src) {
  __shared__ int cnt[256];
  __shared__ int s[256];
  int b = blockIdx.x, t = threadIdx.x;
  int node = b * 256 + t;
  cnt[t] = 0;
  __syncthreads();
  int j0 = edge_base[b], j1 = edge_base[b + 1];
  for (int j = j0 + t; j < j1; j += 256)
    atomicAdd(&cnt[rec[j] & 255], 1);
  __syncthreads();
  int c = (node < NN) ? cnt[t] + 1 : 0;  // +1 self-loop
  s[t] = c;
  __syncthreads();
  for (int off = 1; off < 256; off <<= 1) {
    int u = (t >= off) ? s[t - off] : 0;
    __syncthreads();
    s[t] += u;
    __syncthreads();
  }
  int csr_b = j0 + b * 256;
  int start = csr_b + s[t] - c;
  if (node < NN) {
    row_start[node] = start;
    dinv[node] = rsqrtf((float)c);
    csr_src[start] = node;              // self-loop in slot 0
  }
  __syncthreads();
  cnt[t] = start + 1;                   // reuse as cursor
  __syncthreads();
  for (int j = j0 + t; j < j1; j += 256) {
    int r = rec[j];
    int p = atomicAdd(&cnt[r & 255], 1);
    csr_src[p] = r >> 8;
  }
}

// ---------- MFMA fp16 GEMM: Y[r] = dinv[r] * (X[r] @ W), Y fp16 ----------
// X: [N,128] fp32; W: [128,OUTC] fp32. 64 rows/block, 4 waves, mfma_f32_16x16x32_f16.
template<int OUTC>
__global__ __launch_bounds__(256) void k_gemm_mfma(const float* __restrict__ X,
                                                   const float* __restrict__ W,
                                                   const float* __restrict__ dinv,
                                                   unsigned short* __restrict__ Y) {
  constexpr int NT = OUTC / 16;
  constexpr int PS = 136;              // Wt k-stride (halves)
  constexpr int SS = OUTC + 8;         // out-stage row stride (halves)
  constexpr int WT_H = OUTC * PS;
  constexpr int ST_H = 64 * SS;
  constexpr int SM_H = WT_H > ST_H ? WT_H : ST_H;
  __shared__ _Float16 smem[SM_H];

  const int tid  = threadIdx.x;
  const int lane = tid & 63;
  const int wv   = tid >> 6;
  const int row0 = blockIdx.x * 64;
  const int l15  = lane & 15;
  const int kg   = lane >> 4;

  for (int idx = tid * 4; idx < 128 * OUTC; idx += 1024) {
    float4 v = *(const float4*)&W[idx];
    int k = idx / OUTC, c = idx % OUTC;
    smem[(c + 0) * PS + k] = (_Float16)v.x;
    smem[(c + 1) * PS + k] = (_Float16)v.y;
    smem[(c + 2) * PS + k] = (_Float16)v.z;
    smem[(c + 3) * PS + k] = (_Float16)v.w;
  }
  __syncthreads();

  int arow = row0 + wv * 16 + l15;
  int rr_g = arow < NN ? arow : NN - 1;

  f32x4 acc[NT];
  #pragma unroll
  for (int n = 0; n < NT; n++) acc[n] = (f32x4){0.f, 0.f, 0.f, 0.f};

  #pragma unroll
  for (int kb = 0; kb < 4; kb++) {
    int k0 = kb * 32 + kg * 8;
    f16x8 a;
    float4 v0 = *(const float4*)&X[(size_t)rr_g * 128 + k0];
    float4 v1 = *(const float4*)&X[(size_t)rr_g * 128 + k0 + 4];
    a[0] = (_Float16)v0.x; a[1] = (_Float16)v0.y; a[2] = (_Float16)v0.z; a[3] = (_Float16)v0.w;
    a[4] = (_Float16)v1.x; a[5] = (_Float16)v1.y; a[6] = (_Float16)v1.z; a[7] = (_Float16)v1.w;
    #pragma unroll
    for (int n = 0; n < NT; n++) {
      f16x8 b = *(const f16x8*)&smem[(n * 16 + l15) * PS + k0];
      acc[n] = __builtin_amdgcn_mfma_f32_16x16x32_f16(a, b, acc[n], 0, 0, 0);
    }
  }
  __syncthreads();

  int rb = wv * 16 + kg * 4;
  float dv[4];
  #pragma unroll
  for (int q = 0; q < 4; q++) {
    int gr = row0 + rb + q;
    dv[q] = dinv[gr < NN ? gr : NN - 1];
  }
  #pragma unroll
  for (int n = 0; n < NT; n++)
    #pragma unroll
    for (int q = 0; q < 4; q++)
      smem[(rb + q) * SS + n * 16 + l15] = (_Float16)(acc[n][q] * dv[q]);
  __syncthreads();

  constexpr int SEGS = OUTC / 8;
  for (int u = tid; u < 64 * SEGS; u += 256) {
    int rr = u / SEGS, sg = u % SEGS;
    int gr = row0 + rr;
    if (gr < NN) {
      uint4 v = *(const uint4*)&smem[rr * SS + sg * 8];
      *(uint4*)&Y[(size_t)gr * OUTC + sg * 8] = v;
    }
  }
}

// ---------- fused agg1 + gemm2: Y = dinv * (relu(dinv*Σ h'[s] + b1) @ W2), fp16 ----------
// 16 nodes/block (LPN=16). NN % 16 == 0 so every node is valid.
__global__ __launch_bounds__(256) void k_agg_gemm(const unsigned short* __restrict__ h,
                                                  const float* __restrict__ dinv,
                                                  const int* __restrict__ row_start,
                                                  const int* __restrict__ csr_src,
                                                  const float* __restrict__ bias,
                                                  const float* __restrict__ W,   // W2 [128,64] fp32
                                                  unsigned short* __restrict__ Y) {
  constexpr int PS = 136;   // Wt k-stride (halves)
  constexpr int AS = 136;   // At k-stride (halves)
  constexpr int OS = 72;    // out-stage row stride (halves)
  __shared__ _Float16 Wt[64 * PS];
  __shared__ _Float16 At[16 * AS];   // also reused as out-stage (16*OS <= 16*AS)

  const int tid = threadIdx.x;

  // stage W2 transposed fp16 (runs concurrent with agg; synced before MFMA)
  for (int idx = tid * 4; idx < 128 * 64; idx += 1024) {
    float4 v = *(const float4*)&W[idx];
    int k = idx >> 6, c = idx & 63;
    Wt[(c + 0) * PS + k] = (_Float16)v.x;
    Wt[(c + 1) * PS + k] = (_Float16)v.y;
    Wt[(c + 2) * PS + k] = (_Float16)v.z;
    Wt[(c + 3) * PS + k] = (_Float16)v.w;
  }

  const int ln    = tid & 15;     // feature lane (8 feats each)
  const int lnode = tid >> 4;     // local node 0..15
  const int node  = blockIdx.x * 16 + lnode;

  int j0 = row_start[node], j1 = row_start[node + 1];
  float acc[8] = {};
  #pragma unroll 2
  for (int j = j0; j < j1; j++) {
    int s = csr_src[j];
    uint4 v = *(const uint4*)&h[(size_t)s * 128 + ln * 8];
    float2 f;
    f = h2f2(v.x); acc[0] += f.x; acc[1] += f.y;
    f = h2f2(v.y); acc[2] += f.x; acc[3] += f.y;
    f = h2f2(v.z); acc[4] += f.x; acc[5] += f.y;
    f = h2f2(v.w); acc[6] += f.x; acc[7] += f.y;
  }
  float dn = dinv[node];
  #pragma unroll
  for (int t = 0; t < 8; t++) {
    float o = fmaf(dn, acc[t], bias[ln * 8 + t]);
    o = fmaxf(o, 0.f);                         // relu (layer 1)
    At[lnode * AS + ln * 8 + t] = (_Float16)o; // hmid fp16 A-tile
  }
  __syncthreads();

  // MFMA: 4 waves, wave wv does output col-tile [wv*16, wv*16+16)
  const int lane = tid & 63;
  const int wv   = tid >> 6;
  const int l15  = lane & 15;
  const int kg   = lane >> 4;
  f32x4 dacc = (f32x4){0.f, 0.f, 0.f, 0.f};
  #pragma unroll
  for (int kb = 0; kb < 4; kb++) {
    int k0 = kb * 32 + kg * 8;
    f16x8 a = *(const f16x8*)&At[l15 * AS + k0];
    f16x8 b = *(const f16x8*)&Wt[(wv * 16 + l15) * PS + k0];
    dacc = __builtin_amdgcn_mfma_f32_16x16x32_f16(a, b, dacc, 0, 0, 0);
  }
  __syncthreads();   // done reading At; reuse as out-stage

  #pragma unroll
  for (int q = 0; q < 4; q++) {
    int lr = kg * 4 + q;                        // D row = local node
    float dv = dinv[blockIdx.x * 16 + lr];
    At[lr * OS + wv * 16 + l15] = (_Float16)(dacc[q] * dv);
  }
  __syncthreads();

  for (int u = tid; u < 16 * 8; u += 256) {     // 16 rows x 8 uint4 segs
    int rr = u >> 3, sg = u & 7;
    uint4 v = *(const uint4*)&At[rr * OS + sg * 8];
    *(uint4*)&Y[(size_t)(blockIdx.x * 16 + rr) * 64 + sg * 8] = v;
  }
}

// ---------- final aggregation: out[n] = dinv[n] * Σ hL2[s] + b2 (fp32 out) ----------
__global__ __launch_bounds__(256) void k_agg_final(const unsigned short* __restrict__ h,
                                                   const float* __restrict__ dinv,
                                                   const int* __restrict__ row_start,
                                                   const int* __restrict__ csr_src,
                                                   const float* __restrict__ bias,
                                                   float* __restrict__ out) {
  constexpr int LPN = 8;            // 64 feats / 8 per lane
  int node = blockIdx.x * 32 + threadIdx.x / LPN;
  int lane = threadIdx.x % LPN;
  if (node >= NN) return;
  int j0 = row_start[node], j1 = row_start[node + 1];
  float acc[8] = {};
  #pragma unroll 2
  for (int j = j0; j < j1; j++) {
    int s = csr_src[j];
    uint4 v = *(const uint4*)&h[(size_t)s * 64 + lane * 8];
    float2 f;
    f = h2f2(v.x); acc[0] += f.x; acc[1] += f.y;
    f = h2f2(v.y); acc[2] += f.x; acc[3] += f.y;
    f = h2f2(v.z); acc[4] += f.x; acc[5] += f.y;
    f = h2f2(v.w); acc[6] += f.x; acc[7] += f.y;
  }
  float dn = dinv[node];
  float o[8];
  #pragma unroll
  for (int t = 0; t < 8; t++) o[t] = fmaf(dn, acc[t], bias[lane * 8 + t]);
  *(float4*)&out[(size_t)node * 64 + lane * 8]     = make_float4(o[0], o[1], o[2], o[3]);
  *(float4*)&out[(size_t)node * 64 + lane * 8 + 4] = make_float4(o[4], o[5], o[6], o[7]);
}

// ---------- launch ----------
extern "C" void kernel_launch(void* const* d_in, const int* in_sizes, int n_in,
                              void* d_out, int out_size, void* d_ws, size_t ws_size,
                              hipStream_t stream) {
  const float* x  = (const float*)d_in[0];
  const void*  ei = d_in[1];
  const float* W1 = (const float*)d_in[2];
  const float* b1 = (const float*)d_in[3];
  const float* W2 = (const float*)d_in[4];
  const float* b2 = (const float*)d_in[5];
  float* out = (float*)d_out;

  char* ws = (char*)d_ws;
  size_t off = 0;
  auto wsalloc = [&](size_t bytes) -> void* {
    void* p = ws + off;
    off += (bytes + 255) & ~(size_t)255;
    return p;
  };
  int*            row_start    = (int*)   wsalloc((NN + 1) * sizeof(int));
  int*            hist_g       = (int*)   wsalloc((size_t)NBUK * EBLOCKS * sizeof(int));
  int*            bucket_total = (int*)   wsalloc(NBUK * sizeof(int));
  int*            edge_base    = (int*)   wsalloc((NBUK + 1) * sizeof(int));
  float*          dinv         = (float*) wsalloc(NN * sizeof(float));
  int*            rec          = (int*)   wsalloc((size_t)NE * sizeof(int));      // 6.4 MB packed
  int*            csr_src      = (int*)   wsalloc((size_t)TOT * sizeof(int));
  unsigned short* h1           = (unsigned short*)wsalloc((size_t)NN * 128 * sizeof(unsigned short));
  unsigned short* hL2          = (unsigned short*)wsalloc((size_t)NN * 64 * sizeof(unsigned short));
  // total ws ~ 52 MB

  k_hist<<<EBLOCKS, 256, 0, stream>>>(ei, hist_g);
  k_scan_hist<<<NBUK, EBLOCKS, 0, stream>>>(hist_g, bucket_total);
  k_scan_buckets<<<1, 512, 0, stream>>>(bucket_total, edge_base, row_start);
  k_scatter<<<EBLOCKS, 256, 0, stream>>>(ei, hist_g, edge_base, rec);
  k_bucket_csr<<<NBUK, 256, 0, stream>>>(rec, edge_base, row_start, dinv, csr_src);

  k_gemm_mfma<128><<<(NN + 63) / 64, 256, 0, stream>>>(x, W1, dinv, h1);
  k_agg_gemm<<<NN / 16, 256, 0, stream>>>(h1, dinv, row_start, csr_src, b1, W2, hL2);
  k_agg_final<<<(NN + 31) / 32, 256, 0, stream>>>(hL2, dinv, row_start, csr_src, b2, out);
}